// Round 11
// baseline (1524.256 us; speedup 1.0000x reference)
//
#include <hip/hip_runtime.h>
#include <hip/hip_fp16.h>
#include <math.h>

#define NFEAT 128
#define NCLS  64
#define WSTR  132           // W LDS row stride in halves
#define NBLK  256           // fixed grid for edge-stream passes
#define MAXB  1024          // max buckets (N <= 65536)

// ---------- helpers ----------

typedef _Float16 h2v __attribute__((ext_vector_type(2)));

__device__ __forceinline__ float dot2acc(unsigned int hv, unsigned int wv, float c) {
#if __has_builtin(__builtin_amdgcn_fdot2)
    union { unsigned int u; h2v v; } a, bq; a.u = hv; bq.u = wv;
    return __builtin_amdgcn_fdot2(a.v, bq.v, c, false);
#else
    union { unsigned int u; __half2 h; } a, bq; a.u = hv; bq.u = wv;
    float2 fa = __half22float2(a.h), fb = __half22float2(bq.h);
    return fmaf(fa.x, fb.x, fmaf(fa.y, fb.y, c));
#endif
}

// add one fp16 row-chunk (8 values) into LDS accumulator row d.
// swizzle v=(s+e+4*(q>>2))&7 => every ds_add instr lands 2 lanes/bank (free).
__device__ __forceinline__ void add_edge(float (*acc)[NFEAT], int d, int q, int e,
                                         int qs, uint4 rv) {
    union { uint4 u; __half2 h[4]; } cv; cv.u = rv;
    float f[8];
    #pragma unroll
    for (int t = 0; t < 4; ++t) {
        float2 p = __half22float2(cv.h[t]);
        f[2 * t] = p.x; f[2 * t + 1] = p.y;
    }
    #pragma unroll
    for (int s = 0; s < 8; ++s) {
        int v = (s + e + qs) & 7;
        atomicAdd(&acc[d][q * 8 + v], f[v]);
    }
}

// ---------- build pass 1: per-node in-degree + 64-node-bucket histogram ----------
__global__ __launch_bounds__(256) void histcount_kernel(const int* __restrict__ dst,
                                                        int* __restrict__ cnt,
                                                        int* __restrict__ h,
                                                        int E4, int E, int nb) {
    __shared__ int lh[MAXB];
    const int tid = threadIdx.x;
    for (int t = tid; t < nb; t += 256) lh[t] = 0;
    __syncthreads();
    for (int idx = blockIdx.x * 256 + tid; idx < E4; idx += NBLK * 256) {
        int base = idx * 4;
        if (base + 3 < E) {
            int4 d = ((const int4*)dst)[idx];
            atomicAdd(&cnt[d.x], 1); atomicAdd(&lh[d.x >> 6], 1);
            atomicAdd(&cnt[d.y], 1); atomicAdd(&lh[d.y >> 6], 1);
            atomicAdd(&cnt[d.z], 1); atomicAdd(&lh[d.z >> 6], 1);
            atomicAdd(&cnt[d.w], 1); atomicAdd(&lh[d.w >> 6], 1);
        } else {
            for (int e = base; e < E; ++e) {
                int d = dst[e];
                atomicAdd(&cnt[d], 1); atomicAdd(&lh[d >> 6], 1);
            }
        }
    }
    __syncthreads();
    for (int t = tid; t < nb; t += 256) h[blockIdx.x * nb + t] = lh[t];
}

// pass 2a: per bucket, exclusive scan over its 256 block-counts + total
__global__ __launch_bounds__(256) void colscan_kernel(int* __restrict__ h,
                                                      int* __restrict__ btot, int nb) {
    __shared__ int lds[256];
    const int tid = threadIdx.x;
    const int B = blockIdx.x;
    int v = h[tid * nb + B];
    lds[tid] = v;
    __syncthreads();
    for (int off = 1; off < 256; off <<= 1) {
        int t = (tid >= off) ? lds[tid - off] : 0;
        __syncthreads();
        lds[tid] += t;
        __syncthreads();
    }
    h[tid * nb + B] = lds[tid] - v;                // exclusive within bucket
    if (tid == 255) btot[B] = lds[255];
}

// pass 2b: exclusive scan of bucket totals -> bbase[0..nb]
__global__ __launch_bounds__(1024) void bucket_scan_kernel(const int* __restrict__ btot,
                                                           int* __restrict__ bbase, int nb) {
    __shared__ int lds[MAXB];
    const int tid = threadIdx.x;
    int v = (tid < nb) ? btot[tid] : 0;
    lds[tid] = v;
    __syncthreads();
    for (int off = 1; off < 1024; off <<= 1) {
        int t = (tid >= off) ? lds[tid - off] : 0;
        __syncthreads();
        lds[tid] += t;
        __syncthreads();
    }
    if (tid < nb) bbase[tid + 1] = lds[tid];
    if (tid == 0) bbase[0] = 0;
}

// pass 3: replay edges, write (src,dst) pairs into bucket-ordered COO
__global__ __launch_bounds__(256) void bucket_scatter_kernel(const int* __restrict__ src,
                                                             const int* __restrict__ dst,
                                                             const int* __restrict__ h,
                                                             const int* __restrict__ bbase,
                                                             int2* __restrict__ bedg,
                                                             int E4, int E, int nb) {
    __shared__ int cur[MAXB];
    const int tid = threadIdx.x;
    for (int t = tid; t < nb; t += 256) cur[t] = bbase[t] + h[blockIdx.x * nb + t];
    __syncthreads();
    for (int idx = blockIdx.x * 256 + tid; idx < E4; idx += NBLK * 256) {
        int base = idx * 4;
        if (base + 3 < E) {
            int4 s = ((const int4*)src)[idx];
            int4 d = ((const int4*)dst)[idx];
            int p;
            p = atomicAdd(&cur[d.x >> 6], 1); bedg[p] = make_int2(s.x, d.x);
            p = atomicAdd(&cur[d.y >> 6], 1); bedg[p] = make_int2(s.y, d.y);
            p = atomicAdd(&cur[d.z >> 6], 1); bedg[p] = make_int2(s.z, d.z);
            p = atomicAdd(&cur[d.w >> 6], 1); bedg[p] = make_int2(s.w, d.w);
        } else {
            for (int e = base; e < E; ++e) {
                int p = atomicAdd(&cur[dst[e] >> 6], 1);
                bedg[p] = make_int2(src[e], dst[e]);
            }
        }
    }
}

// ---------- prep: xh = fp16(dinv * x); also emits dinv ----------
__global__ void prep_kernel(const float* __restrict__ x, const int* __restrict__ cnt,
                            __half* __restrict__ xh, float* __restrict__ dinv, int N) {
    int idx = blockIdx.x * blockDim.x + threadIdx.x;   // one float4 / uint2 per thread
    if (idx < N * 32) {
        int i = idx >> 5, c = idx & 31;
        float d = rsqrtf((float)cnt[i] + 1.0f);        // +1 self-loop
        float4 v = ((const float4*)x)[idx];
        union { uint2 u; __half2 h[2]; } r;
        r.h[0] = __floats2half2_rn(d * v.x, d * v.y);
        r.h[1] = __floats2half2_rn(d * v.z, d * v.w);
        ((uint2*)xh)[idx] = r.u;
        if (c == 0) dinv[i] = d;
    }
}

// ---------- hop 1 from bucketed COO: y1[i] = fp16(dinv_i^2 * (sum xh_j + xh_i)) ----------
__global__ __launch_bounds__(256) void hop1_coo(const __half* __restrict__ xh,
                                                const float* __restrict__ dinv,
                                                const int* __restrict__ bbase,
                                                const int2* __restrict__ bedg,
                                                __half* __restrict__ y1h, int N) {
    __shared__ float acc[64][NFEAT];                   // 32 KB
    const int tid = threadIdx.x;
    const int w = tid >> 6, lane = tid & 63;
    const int e = lane >> 4, q = lane & 15;
    const int qs = 4 * (q >> 2);
    const int n0 = blockIdx.x * 64;
    const uint4* X = (const uint4*)xh;

    // self-term init (acc[n] = xh[n0+n])
    #pragma unroll
    for (int it = 0; it < 4; ++it) {
        int idx = it * 256 + tid;
        int n = idx >> 4, c = idx & 15;
        if (n0 + n < N) {
            union { uint4 u; __half2 h[4]; } cv;
            cv.u = X[(size_t)(n0 + n) * 16 + c];
            float* a = &acc[n][c * 8];
            #pragma unroll
            for (int t = 0; t < 4; ++t) {
                float2 f = __half22float2(cv.h[t]);
                a[2 * t] = f.x; a[2 * t + 1] = f.y;
            }
        }
    }
    __syncthreads();

    const int s0 = bbase[blockIdx.x], s1 = bbase[blockIdx.x + 1];
    for (int k0 = s0 + w * 16; k0 < s1; k0 += 64) {    // 16 edges per wave-round
        int ke = k0 + e;
        int2 E0 = bedg[min(ke,      s1 - 1)];
        int2 E1 = bedg[min(ke + 4,  s1 - 1)];
        int2 E2 = bedg[min(ke + 8,  s1 - 1)];
        int2 E3 = bedg[min(ke + 12, s1 - 1)];
        uint4 r0 = X[(size_t)E0.x * 16 + q];           // 4 row loads in flight
        uint4 r1 = X[(size_t)E1.x * 16 + q];
        uint4 r2 = X[(size_t)E2.x * 16 + q];
        uint4 r3 = X[(size_t)E3.x * 16 + q];
        if (ke      < s1) add_edge(acc, E0.y - n0, q, e, qs, r0);
        if (ke + 4  < s1) add_edge(acc, E1.y - n0, q, e, qs, r1);
        if (ke + 8  < s1) add_edge(acc, E2.y - n0, q, e, qs, r2);
        if (ke + 12 < s1) add_edge(acc, E3.y - n0, q, e, qs, r3);
    }
    __syncthreads();

    // epilogue: y1 = dinv^2 * acc, fp16
    #pragma unroll
    for (int it = 0; it < 4; ++it) {
        int idx = it * 256 + tid;
        int n = idx >> 4, c = idx & 15;
        if (n0 + n < N) {
            float di = dinv[n0 + n];
            float s = di * di;
            const float* a = &acc[n][c * 8];
            union { uint4 u; __half2 h[4]; } r;
            #pragma unroll
            for (int t = 0; t < 4; ++t)
                r.h[t] = __floats2half2_rn(s * a[2 * t], s * a[2 * t + 1]);
            ((uint4*)y1h)[(size_t)(n0 + n) * 16 + c] = r.u;
        }
    }
}

// ---------- hop 2 + classifier fused: x2 = dinv*(sum y1 + y1_self); ----------
// ---------- logits = x2 @ W^T + b; log_softmax -> out ----------
__global__ __launch_bounds__(256) void hop2cls_coo(const __half* __restrict__ y1h,
                                                   const float* __restrict__ dinv,
                                                   const int* __restrict__ bbase,
                                                   const int2* __restrict__ bedg,
                                                   const float* __restrict__ W,
                                                   const float* __restrict__ b,
                                                   float* __restrict__ out, int N) {
    __shared__ float acc[64][NFEAT];                   // 32 KB
    __shared__ __half Wl[NCLS * WSTR];                 // 16.9 KB
    const int tid = threadIdx.x;
    const int w = tid >> 6, lane = tid & 63;
    const int e = lane >> 4, q = lane & 15;
    const int qs = 4 * (q >> 2);
    const int n0 = blockIdx.x * 64;
    const uint4* X = (const uint4*)y1h;

    // stage W (fp16) + self-term init
    for (int t = tid; t < NCLS * NFEAT; t += 256) {
        int r = t >> 7, c = t & 127;
        Wl[r * WSTR + c] = __float2half(W[t]);
    }
    #pragma unroll
    for (int it = 0; it < 4; ++it) {
        int idx = it * 256 + tid;
        int n = idx >> 4, c = idx & 15;
        if (n0 + n < N) {
            union { uint4 u; __half2 h[4]; } cv;
            cv.u = X[(size_t)(n0 + n) * 16 + c];
            float* a = &acc[n][c * 8];
            #pragma unroll
            for (int t = 0; t < 4; ++t) {
                float2 f = __half22float2(cv.h[t]);
                a[2 * t] = f.x; a[2 * t + 1] = f.y;
            }
        }
    }
    __syncthreads();

    // W row `lane` (= class) into 64 VGPRs
    unsigned int wreg[64];
    {
        const uint2* wr = (const uint2*)&Wl[lane * WSTR];
        #pragma unroll
        for (int t = 0; t < 32; ++t) {
            uint2 v = wr[t];
            wreg[2 * t] = v.x; wreg[2 * t + 1] = v.y;
        }
    }
    const float breg = b[lane];

    const int s0 = bbase[blockIdx.x], s1 = bbase[blockIdx.x + 1];
    for (int k0 = s0 + w * 16; k0 < s1; k0 += 64) {
        int ke = k0 + e;
        int2 E0 = bedg[min(ke,      s1 - 1)];
        int2 E1 = bedg[min(ke + 4,  s1 - 1)];
        int2 E2 = bedg[min(ke + 8,  s1 - 1)];
        int2 E3 = bedg[min(ke + 12, s1 - 1)];
        uint4 r0 = X[(size_t)E0.x * 16 + q];
        uint4 r1 = X[(size_t)E1.x * 16 + q];
        uint4 r2 = X[(size_t)E2.x * 16 + q];
        uint4 r3 = X[(size_t)E3.x * 16 + q];
        if (ke      < s1) add_edge(acc, E0.y - n0, q, e, qs, r0);
        if (ke + 4  < s1) add_edge(acc, E1.y - n0, q, e, qs, r1);
        if (ke + 8  < s1) add_edge(acc, E2.y - n0, q, e, qs, r2);
        if (ke + 12 < s1) add_edge(acc, E3.y - n0, q, e, qs, r3);
    }
    __syncthreads();

    // scale by dinv and pack rows to fp16 in place (lower 64 uint slots per row)
    {
        int n = tid & 63;
        int hh = tid >> 6;                              // 0..3
        float di = dinv[min(n0 + n, N - 1)];
        unsigned int pk[16];
        #pragma unroll
        for (int j = 0; j < 16; ++j) {
            int v = hh * 16 + j;
            union { unsigned int u; __half2 h; } r;
            r.h = __floats2half2_rn(di * acc[n][2 * v], di * acc[n][2 * v + 1]);
            pk[j] = r.u;
        }
        __syncthreads();
        unsigned int* urow = (unsigned int*)&acc[n][0];
        #pragma unroll
        for (int j = 0; j < 16; ++j) urow[hh * 16 + j] = pk[j];
    }
    __syncthreads();

    // classifier: each wave handles 16 nodes; h reads are wave-broadcast
    #pragma unroll 1
    for (int r = 0; r < 16; ++r) {
        int nn = w * 16 + r;
        int node = n0 + nn;
        if (node < N) {
            const unsigned int* hrow = (const unsigned int*)&acc[nn][0];
            float dot = breg;
            #pragma unroll
            for (int t = 0; t < 64; ++t)
                dot = dot2acc(hrow[t], wreg[t], dot);
            float m = dot;
            for (int o = 32; o > 0; o >>= 1) m = fmaxf(m, __shfl_xor(m, o));
            float ex = __expf(dot - m);
            float se = ex;
            for (int o = 32; o > 0; o >>= 1) se += __shfl_xor(se, o);
            out[(size_t)node * NCLS + lane] = dot - m - logf(se);
        }
    }
}

// ---------- launch ----------

static inline size_t align256(size_t v) { return (v + 255) & ~(size_t)255; }

extern "C" void kernel_launch(void* const* d_in, const int* in_sizes, int n_in,
                              void* d_out, int out_size, void* d_ws, size_t ws_size,
                              hipStream_t stream) {
    const float* x  = (const float*)d_in[0];
    const int*   ei = (const int*)d_in[1];
    const float* W  = (const float*)d_in[2];
    const float* b  = (const float*)d_in[3];
    float* out = (float*)d_out;

    const int N = in_sizes[0] / NFEAT;   // 50000
    const int E = in_sizes[1] / 2;       // 800000
    const int* src = ei;
    const int* dst = ei + E;
    const int NB2 = (N + 63) >> 6;       // 782 buckets of 64 nodes

    char* ws = (char*)d_ws;
    size_t o = 0;
    int*    cnt   = (int*)(ws + o);    o += align256((size_t)N * 4);
    float*  dinv  = (float*)(ws + o);  o += align256((size_t)N * 4);
    int*    h     = (int*)(ws + o);    o += align256((size_t)NBLK * NB2 * 4);
    int*    btot  = (int*)(ws + o);    o += align256((size_t)MAXB * 4);
    int*    bbase = (int*)(ws + o);    o += align256((size_t)(MAXB + 1) * 4);
    int2*   bedg  = (int2*)(ws + o);   o += align256((size_t)E * 8);
    __half* xh    = (__half*)(ws + o); o += align256((size_t)N * NFEAT * 2);
    __half* y1h   = (__half*)(ws + o); o += align256((size_t)N * NFEAT * 2);

    const int E4 = (E + 3) / 4;

    hipMemsetAsync(cnt, 0, (size_t)N * 4, stream);
    histcount_kernel<<<NBLK, 256, 0, stream>>>(dst, cnt, h, E4, E, NB2);
    colscan_kernel<<<NB2, 256, 0, stream>>>(h, btot, NB2);
    bucket_scan_kernel<<<1, 1024, 0, stream>>>(btot, bbase, NB2);
    bucket_scatter_kernel<<<NBLK, 256, 0, stream>>>(src, dst, h, bbase, bedg, E4, E, NB2);
    prep_kernel<<<(N * 32 + 255) / 256, 256, 0, stream>>>(x, cnt, xh, dinv, N);
    hop1_coo<<<NB2, 256, 0, stream>>>(xh, dinv, bbase, bedg, y1h, N);
    hop2cls_coo<<<NB2, 256, 0, stream>>>(y1h, dinv, bbase, bedg, W, b, out, N);
}

// Round 12
// 191.585 us; speedup vs baseline: 7.9560x; 7.9560x over previous
//
#include <hip/hip_runtime.h>
#include <hip/hip_fp16.h>
#include <math.h>

#define NFEAT 128
#define NCLS  64
#define RQ    16            // uint4 per fp16 row (256 B)
#define WSTR  132           // W LDS row stride in halves
#define NBLK  256           // grid for edge-stream passes

// ---------- helpers ----------

typedef _Float16 h2v __attribute__((ext_vector_type(2)));

__device__ __forceinline__ float dot2acc(unsigned int hv, unsigned int wv, float c) {
#if __has_builtin(__builtin_amdgcn_fdot2)
    union { unsigned int u; h2v v; } a, bq; a.u = hv; bq.u = wv;
    return __builtin_amdgcn_fdot2(a.v, bq.v, c, false);
#else
    union { unsigned int u; __half2 h; } a, bq; a.u = hv; bq.u = wv;
    float2 fa = __half22float2(a.h), fb = __half22float2(bq.h);
    return fmaf(fa.x, fb.x, fmaf(fa.y, fb.y, c));
#endif
}

// packed fp16 accumulate: 4 v_pk_add_f16 per 16B row-chunk (3x fewer VALU than fp32 path)
__device__ __forceinline__ void acc4(__half2 a[4], uint4 v) {
    union { uint4 u; __half2 h[4]; } c; c.u = v;
    a[0] = __hadd2(a[0], c.h[0]); a[1] = __hadd2(a[1], c.h[1]);
    a[2] = __hadd2(a[2], c.h[2]); a[3] = __hadd2(a[3], c.h[3]);
}

__device__ __forceinline__ __half2 red2(__half2 a) {   // reduce across 4 sub-slots
    union { __half2 h; int i; } u, v;
    u.h = a; v.i = __shfl_xor(u.i, 16); a = __hadd2(a, v.h);
    u.h = a; v.i = __shfl_xor(u.i, 32); a = __hadd2(a, v.h);
    return a;
}

// ---------- build pass 1: 256-node-bucket histogram only (no global cnt) ----------
__global__ __launch_bounds__(256) void hist_kernel(const int* __restrict__ dst,
                                                   int* __restrict__ h,
                                                   int E4, int E, int nb) {
    __shared__ int lh[256];
    const int tid = threadIdx.x;
    lh[tid] = 0;
    __syncthreads();
    for (int idx = blockIdx.x * 256 + tid; idx < E4; idx += NBLK * 256) {
        int base = idx * 4;
        if (base + 3 < E) {
            int4 d = ((const int4*)dst)[idx];
            atomicAdd(&lh[d.x >> 8], 1); atomicAdd(&lh[d.y >> 8], 1);
            atomicAdd(&lh[d.z >> 8], 1); atomicAdd(&lh[d.w >> 8], 1);
        } else {
            for (int e = base; e < E; ++e) atomicAdd(&lh[dst[e] >> 8], 1);
        }
    }
    __syncthreads();
    if (tid < nb) h[blockIdx.x * nb + tid] = lh[tid];
}

// pass 2a: per bucket, exclusive scan over its 256 block-counts + total
__global__ __launch_bounds__(256) void colscan_kernel(int* __restrict__ h,
                                                      int* __restrict__ btot, int nb) {
    __shared__ int lds[256];
    const int tid = threadIdx.x;
    const int B = blockIdx.x;
    int v = h[tid * nb + B];
    lds[tid] = v;
    __syncthreads();
    for (int off = 1; off < 256; off <<= 1) {
        int t = (tid >= off) ? lds[tid - off] : 0;
        __syncthreads();
        lds[tid] += t;
        __syncthreads();
    }
    h[tid * nb + B] = lds[tid] - v;                // exclusive within bucket
    if (tid == 255) btot[B] = lds[255];
}

// pass 2b: exclusive scan of bucket totals -> bbase[0..nb]
__global__ __launch_bounds__(256) void bucket_scan_kernel(const int* __restrict__ btot,
                                                          int* __restrict__ bbase, int nb) {
    __shared__ int lds[256];
    const int tid = threadIdx.x;
    int v = (tid < nb) ? btot[tid] : 0;
    lds[tid] = v;
    __syncthreads();
    for (int off = 1; off < 256; off <<= 1) {
        int t = (tid >= off) ? lds[tid - off] : 0;
        __syncthreads();
        lds[tid] += t;
        __syncthreads();
    }
    if (tid < nb) bbase[tid + 1] = lds[tid];
    if (tid == 0) bbase[0] = 0;
}

// pass 3: replay edges, write (src,dst) pairs into bucket-ordered COO
__global__ __launch_bounds__(256) void bucket_scatter_kernel(const int* __restrict__ src,
                                                             const int* __restrict__ dst,
                                                             const int* __restrict__ h,
                                                             const int* __restrict__ bbase,
                                                             int2* __restrict__ bedg,
                                                             int E4, int E, int nb) {
    __shared__ int cur[256];
    const int tid = threadIdx.x;
    if (tid < nb) cur[tid] = bbase[tid] + h[blockIdx.x * nb + tid];
    __syncthreads();
    for (int idx = blockIdx.x * 256 + tid; idx < E4; idx += NBLK * 256) {
        int base = idx * 4;
        if (base + 3 < E) {
            int4 s = ((const int4*)src)[idx];
            int4 d = ((const int4*)dst)[idx];
            int p;
            p = atomicAdd(&cur[d.x >> 8], 1); bedg[p] = make_int2(s.x, d.x);
            p = atomicAdd(&cur[d.y >> 8], 1); bedg[p] = make_int2(s.y, d.y);
            p = atomicAdd(&cur[d.z >> 8], 1); bedg[p] = make_int2(s.z, d.z);
            p = atomicAdd(&cur[d.w >> 8], 1); bedg[p] = make_int2(s.w, d.w);
        } else {
            for (int e = base; e < E; ++e) {
                int p = atomicAdd(&cur[dst[e] >> 8], 1);
                bedg[p] = make_int2(src[e], dst[e]);
            }
        }
    }
}

// pass 4: per-bucket LDS counting sort -> csr rows (padded x4, pads = N),
// rbeg/rend, dinv. All cursors in LDS; csr writes confined to one bucket slice.
__global__ __launch_bounds__(256) void drain_kernel(const int2* __restrict__ bedg,
                                                    const int* __restrict__ bbase,
                                                    int* __restrict__ csr,
                                                    int* __restrict__ rbeg,
                                                    int* __restrict__ rend,
                                                    float* __restrict__ dinv, int N) {
    __shared__ int lcnt[256];
    __shared__ int lds[256];
    __shared__ int loc[256];
    const int B = blockIdx.x;
    const int tid = threadIdx.x;
    const int s0 = bbase[B], s1 = bbase[B + 1];

    lcnt[tid] = 0;
    __syncthreads();
    for (int e = s0 + tid; e < s1; e += 256)
        atomicAdd(&lcnt[bedg[e].y & 255], 1);
    __syncthreads();

    const int c = lcnt[tid];
    const int cp = (c + 3) & ~3;                   // padded row length
    lds[tid] = cp;
    __syncthreads();
    for (int off = 1; off < 256; off <<= 1) {      // exclusive scan of padded lens
        int t = (tid >= off) ? lds[tid - off] : 0;
        __syncthreads();
        lds[tid] += t;
        __syncthreads();
    }
    const int base = bbase[B] + 768 * B;           // per-bucket csr slack: +768
    loc[tid] = base + lds[tid] - cp;               // row start
    __syncthreads();
    lcnt[tid] = loc[tid];                          // reuse as cursor
    __syncthreads();

    for (int e = s0 + tid; e < s1; e += 256) {
        int2 Ev = bedg[e];
        int p = atomicAdd(&lcnt[Ev.y & 255], 1);
        csr[p] = Ev.x;
    }
    __syncthreads();

    int i = B * 256 + tid;
    if (i < N) {
        int start = loc[tid], end = start + cp;
        for (int p = lcnt[tid]; p < end; ++p) csr[p] = N;   // <=3 pads (dummy row)
        rbeg[i] = start; rend[i] = end;
        dinv[i] = rsqrtf((float)c + 1.0f);         // +1 self-loop
    }
}

// ---------- prep: xh = fp16(dinv*x); zero dummy row N of xh & y1h ----------
__global__ void prep_kernel(const float* __restrict__ x, const float* __restrict__ dinv,
                            __half* __restrict__ xh, __half* __restrict__ y1h, int N) {
    int idx = blockIdx.x * blockDim.x + threadIdx.x;   // one float4/uint2 per thread
    int total = N * 32;
    if (idx < total) {
        float d = dinv[idx >> 5];
        float4 v = ((const float4*)x)[idx];
        union { uint2 u; __half2 h[2]; } r;
        r.h[0] = __floats2half2_rn(d * v.x, d * v.y);
        r.h[1] = __floats2half2_rn(d * v.z, d * v.w);
        ((uint2*)xh)[idx] = r.u;
    } else if (idx < total + 32) {
        ((uint2*)xh)[idx] = uint2{0, 0};
    } else if (idx < total + 64) {
        ((uint2*)y1h)[idx - 32] = uint2{0, 0};
    }
}

// ---------- gather core: 16-edge main loop, batched tail, fp16 accumulate ----------
__device__ __forceinline__ void gather_row(__half2 a[4], const uint4* __restrict__ X,
                                           const int* __restrict__ csr,
                                           int ks, int ke, int sub, int q, int Nd) {
    int k = ks;
    int j0, j1, j2, j3;
    bool have = (k + 16 <= ke);
    if (have) {
        j0 = csr[k + sub]; j1 = csr[k + 4 + sub];
        j2 = csr[k + 8 + sub]; j3 = csr[k + 12 + sub];
    }
    while (have) {
        uint4 v0 = X[(size_t)j0 * RQ + q];
        uint4 v1 = X[(size_t)j1 * RQ + q];
        uint4 v2 = X[(size_t)j2 * RQ + q];
        uint4 v3 = X[(size_t)j3 * RQ + q];
        k += 16;
        have = (k + 16 <= ke);
        if (have) {                               // prefetch next indices
            j0 = csr[k + sub]; j1 = csr[k + 4 + sub];
            j2 = csr[k + 8 + sub]; j3 = csr[k + 12 + sub];
        }
        acc4(a, v0); acc4(a, v1); acc4(a, v2); acc4(a, v3);
    }
    int rem = (ke - k) >> 2;                      // 0..3, wave-uniform
    if (rem) {
        int t0 = csr[k + sub];
        int t1 = csr[k + 4 + sub];      // overrun reads land in bucket slack (garbage)
        int t2 = csr[k + 8 + sub];      // but are discarded via redirect below
        if (rem < 2) t1 = Nd;
        if (rem < 3) t2 = Nd;
        uint4 v0 = X[(size_t)t0 * RQ + q];
        uint4 v1 = X[(size_t)t1 * RQ + q];
        uint4 v2 = X[(size_t)t2 * RQ + q];
        acc4(a, v0); acc4(a, v1); acc4(a, v2);
    }
}

// ---------- generic hop: out[i] = fp16( scale_i * (sum_j in[j] + in[i]) ) ----------
template <int SQUARE>
__global__ __launch_bounds__(256) void hop_kernel(const __half* __restrict__ in_h,
                                                  const float* __restrict__ dinv,
                                                  const int* __restrict__ rbeg,
                                                  const int* __restrict__ rend,
                                                  const int* __restrict__ csr,
                                                  __half* __restrict__ out_h, int N) {
    const int tid = threadIdx.x;
    const int w = tid >> 6, lane = tid & 63;
    const int i = blockIdx.x * 4 + w;
    if (i >= N) return;                           // wave-uniform; no barriers
    const int sub = lane >> 4;
    const int q = lane & 15;
    const uint4* X = (const uint4*)in_h;

    __half2 a[4];
    a[0] = __float2half2_rn(0.f); a[1] = a[0]; a[2] = a[0]; a[3] = a[0];

    int ks = rbeg[i], ke = rend[i];
    gather_row(a, X, csr, ks, ke, sub, q, N);
    if (sub == 0) acc4(a, X[(size_t)i * RQ + q]);   // self term

    a[0] = red2(a[0]); a[1] = red2(a[1]); a[2] = red2(a[2]); a[3] = red2(a[3]);

    if (sub == 0) {
        float di = dinv[i];
        float s = SQUARE ? di * di : di;
        union { uint4 u; __half2 h[4]; } r;
        #pragma unroll
        for (int t = 0; t < 4; ++t) {
            float2 f = __half22float2(a[t]);
            r.h[t] = __floats2half2_rn(s * f.x, s * f.y);
        }
        ((uint4*)out_h)[(size_t)i * RQ + q] = r.u;
    }
}

// ---------- classifier: logits = x2 @ W^T + b, log_softmax ----------
__global__ __launch_bounds__(512) void cls_kernel(const __half* __restrict__ x2h,
                                                  const float* __restrict__ W,
                                                  const float* __restrict__ b,
                                                  float* __restrict__ out, int N) {
    __shared__ __half Wl[NCLS * WSTR];
    __shared__ __align__(16) __half HT[64][NFEAT];

    const int tid = threadIdx.x;
    const int w = tid >> 6, lane = tid & 63;

    for (int e = tid; e < NCLS * NFEAT; e += 512) {
        int r = e >> 7, c = e & 127;
        Wl[r * WSTR + c] = __float2half(W[e]);
    }
    const size_t base = (size_t)blockIdx.x * 64 * NFEAT;
    {
        const uint4* src = (const uint4*)(x2h + base);   // slack-allocated: safe overrun
        uint4* dst = (uint4*)&HT[0][0];
        dst[tid] = src[tid];
        dst[tid + 512] = src[tid + 512];
    }
    __syncthreads();

    unsigned int wreg[64];
    {
        const uint2* wr = (const uint2*)&Wl[lane * WSTR];
        #pragma unroll
        for (int t = 0; t < 32; ++t) {
            uint2 v = wr[t];
            wreg[2 * t] = v.x; wreg[2 * t + 1] = v.y;
        }
    }
    const float breg = b[lane];

    #pragma unroll 1
    for (int r = 0; r < 8; ++r) {
        int node = blockIdx.x * 64 + w * 8 + r;
        if (node >= N) break;
        const unsigned int* hrow = (const unsigned int*)&HT[w * 8 + r][0];
        float dot = breg;
        #pragma unroll
        for (int t = 0; t < 64; ++t)
            dot = dot2acc(hrow[t], wreg[t], dot);

        float m = dot;
        for (int o = 32; o > 0; o >>= 1) m = fmaxf(m, __shfl_xor(m, o));
        float ex = __expf(dot - m);
        float se = ex;
        for (int o = 32; o > 0; o >>= 1) se += __shfl_xor(se, o);
        out[(size_t)node * NCLS + lane] = dot - m - logf(se);
    }
}

// ---------- launch ----------

static inline size_t align256(size_t v) { return (v + 255) & ~(size_t)255; }

extern "C" void kernel_launch(void* const* d_in, const int* in_sizes, int n_in,
                              void* d_out, int out_size, void* d_ws, size_t ws_size,
                              hipStream_t stream) {
    const float* x  = (const float*)d_in[0];
    const int*   ei = (const int*)d_in[1];
    const float* W  = (const float*)d_in[2];
    const float* b  = (const float*)d_in[3];
    float* out = (float*)d_out;

    const int N = in_sizes[0] / NFEAT;   // 50000
    const int E = in_sizes[1] / 2;       // 800000
    const int* src = ei;
    const int* dst = ei + E;
    const int NBUCK = (N + 255) >> 8;    // 196 buckets of 256 nodes

    const int CSR_CAP = E + 768 * NBUCK + 64;   // per-bucket pad slack + overrun slack

    char* ws = (char*)d_ws;
    size_t o = 0;
    int*    h     = (int*)(ws + o);    o += align256((size_t)NBLK * NBUCK * 4);
    int*    btot  = (int*)(ws + o);    o += align256(256 * 4);
    int*    bbase = (int*)(ws + o);    o += align256(257 * 4);
    int2*   bedg  = (int2*)(ws + o);   o += align256((size_t)E * 8);
    int*    csr   = (int*)(ws + o);    o += align256((size_t)CSR_CAP * 4);
    int*    rbeg  = (int*)(ws + o);    o += align256((size_t)N * 4);
    int*    rend  = (int*)(ws + o);    o += align256((size_t)N * 4);
    float*  dinv  = (float*)(ws + o);  o += align256((size_t)N * 4);
    __half* xh    = (__half*)(ws + o); o += align256((size_t)(N + 64) * NFEAT * 2);
    __half* y1h   = (__half*)(ws + o); o += align256((size_t)(N + 1) * NFEAT * 2);
    __half* x2h   = xh;                // xh dead after hop1; reuse (has +64 row slack for cls)

    const int E4 = (E + 3) / 4;

    hist_kernel<<<NBLK, 256, 0, stream>>>(dst, h, E4, E, NBUCK);
    colscan_kernel<<<NBUCK, 256, 0, stream>>>(h, btot, NBUCK);
    bucket_scan_kernel<<<1, 256, 0, stream>>>(btot, bbase, NBUCK);
    bucket_scatter_kernel<<<NBLK, 256, 0, stream>>>(src, dst, h, bbase, bedg, E4, E, NBUCK);
    drain_kernel<<<NBUCK, 256, 0, stream>>>(bedg, bbase, csr, rbeg, rend, dinv, N);
    prep_kernel<<<(N * 32 + 64 + 255) / 256, 256, 0, stream>>>(x, dinv, xh, y1h, N);
    hop_kernel<1><<<(N + 3) / 4, 256, 0, stream>>>(xh, dinv, rbeg, rend, csr, y1h, N);
    hop_kernel<0><<<(N + 3) / 4, 256, 0, stream>>>(y1h, dinv, rbeg, rend, csr, x2h, N);
    cls_kernel<<<(N + 63) / 64, 512, 0, stream>>>(x2h, W, b, out, N);
}